// Round 5
// baseline (79.432 us; speedup 1.0000x reference)
//
#include <hip/hip_runtime.h>
#include <cstdint>

#define NB 32
#define NC 512
#define NQ 64
#define ND 512

typedef __attribute__((ext_vector_type(8))) short bf16x8;   // 8 bf16 (4 VGPRs)
typedef __attribute__((ext_vector_type(4))) float f32x4;

__device__ __forceinline__ short f2bf(float f) {   // RNE f32 -> bf16
  union { float f; unsigned u; } v; v.f = f;
  v.u += 0x7fffu + ((v.u >> 16) & 1u);
  return (short)(v.u >> 16);
}

// LDS layout (short units). PITCH=72 shorts (144 B rows, 16B-aligned fragments)
#define PITCH 72
#define P_OFF  0       // P bf16 [64 c][72]     (persists through phase B)
#define CM_OFF 4608    // phase A: ctx*w_m [64][72]; phase B: qT [64 d][72 q]
#define QQ_OFF 9216    // phase A: query [64 q][72]
#define SCS_F  6912    // float idx: s_c[64]  (shorts 13824..13952)
#define SQS_F  6976    // float idx: s_q[64]  (shorts 13952..14080)
#define SM_SHORTS 14080

__device__ __forceinline__ int qswz(int dd) {  // q-block XOR swizzle for qT row dd
  return (((dd & 7) ^ ((dd >> 3) & 7)) * 8);
}

// ============ kA: GEMM1 + softmax + GEMM2; writes G part 1 (aq) + m_ws ============
// Structure identical to the R2 kernel that passed graph-replay validation;
// only the epilogue differs (direct f32 scalar stores of aq, no LDS spill).
__global__ __launch_bounds__(256) void kA(
    const float* __restrict__ ctx, const float* __restrict__ qry,
    const float* __restrict__ W, float* __restrict__ G, float* __restrict__ m_ws)
{
  __shared__ __align__(16) short sm[SM_SHORTS];
  float* smf = (float*)sm;

  const int t    = threadIdx.x;
  const int lane = t & 63;
  const int w    = t >> 6;        // wave owns c-rows w*16..+15
  const int ln15 = lane & 15;
  const int g    = lane >> 4;
  const int b    = blockIdx.x >> 3;
  const int c0   = (blockIdx.x & 7) * 64;

  const int srow = t >> 4;        // loader: 16 lanes per 64-float row segment
  const int scol = (t & 15) * 4;

  f32x4 acc[4] = {};
  float scp[4] = {0,0,0,0}, sqp[4] = {0,0,0,0};

  // ---------- Phase A: S = (ctx*w_m) @ query^T, K=512 in 8 chunks ----------
  for (int kc = 0; kc < 8; ++kc) {
    const int d0 = kc * 64;
    const float4 wc = *(const float4*)(W + d0 + scol);
    const float4 wq = *(const float4*)(W + ND + d0 + scol);
    const float4 wm = *(const float4*)(W + 2*ND + d0 + scol);
    __syncthreads();
    #pragma unroll
    for (int k4 = 0; k4 < 4; ++k4) {
      const int r = k4*16 + srow;
      const float4 cv = *(const float4*)(ctx + ((size_t)(b*NC + c0 + r))*ND + d0 + scol);
      const float4 qv = *(const float4*)(qry + ((size_t)(b*NQ + r))*ND + d0 + scol);
      scp[k4] += cv.x*wc.x + cv.y*wc.y + cv.z*wc.z + cv.w*wc.w;
      sqp[k4] += qv.x*wq.x + qv.y*wq.y + qv.z*wq.z + qv.w*wq.w;
      short4 cs; cs.x = f2bf(cv.x*wm.x); cs.y = f2bf(cv.y*wm.y);
                 cs.z = f2bf(cv.z*wm.z); cs.w = f2bf(cv.w*wm.w);
      short4 qs; qs.x = f2bf(qv.x); qs.y = f2bf(qv.y);
                 qs.z = f2bf(qv.z); qs.w = f2bf(qv.w);
      *(short4*)&sm[CM_OFF + r*PITCH + scol] = cs;
      *(short4*)&sm[QQ_OFF + r*PITCH + scol] = qs;
    }
    __syncthreads();
    #pragma unroll
    for (int kk = 0; kk < 2; ++kk) {
      const bf16x8 a = *(const bf16x8*)&sm[CM_OFF + (w*16 + ln15)*PITCH + kk*32 + g*8];
      #pragma unroll
      for (int n = 0; n < 4; ++n) {
        const bf16x8 bq = *(const bf16x8*)&sm[QQ_OFF + (n*16 + ln15)*PITCH + kk*32 + g*8];
        acc[n] = __builtin_amdgcn_mfma_f32_16x16x32_bf16(a, bq, acc[n], 0, 0, 0);
      }
    }
  }

  // s_c / s_q: reduce each owned row across its 16 lanes
  #pragma unroll
  for (int k4 = 0; k4 < 4; ++k4) {
    float v = scp[k4], u = sqp[k4];
    v += __shfl_xor(v, 1, 16); v += __shfl_xor(v, 2, 16);
    v += __shfl_xor(v, 4, 16); v += __shfl_xor(v, 8, 16);
    u += __shfl_xor(u, 1, 16); u += __shfl_xor(u, 2, 16);
    u += __shfl_xor(u, 4, 16); u += __shfl_xor(u, 8, 16);
    if (ln15 == 0) { smf[SCS_F + k4*16 + srow] = v; smf[SQS_F + k4*16 + srow] = u; }
  }
  __syncthreads();

  // ---------- softmax over q (s_c cancels; added only to stored rowmax) ----------
  #pragma unroll
  for (int reg = 0; reg < 4; ++reg) {
    const int rloc = w*16 + g*4 + reg;   // local c (C/D row mapping)
    float sv[4];
    #pragma unroll
    for (int n = 0; n < 4; ++n) sv[n] = acc[n][reg] + smf[SQS_F + ln15 + 16*n];
    float mx = fmaxf(fmaxf(sv[0], sv[1]), fmaxf(sv[2], sv[3]));
    mx = fmaxf(mx, __shfl_xor(mx, 1, 16));
    mx = fmaxf(mx, __shfl_xor(mx, 2, 16));
    mx = fmaxf(mx, __shfl_xor(mx, 4, 16));
    mx = fmaxf(mx, __shfl_xor(mx, 8, 16));
    float s = 0.f;
    #pragma unroll
    for (int n = 0; n < 4; ++n) { sv[n] = __expf(sv[n] - mx); s += sv[n]; }
    s += __shfl_xor(s, 1, 16); s += __shfl_xor(s, 2, 16);
    s += __shfl_xor(s, 4, 16); s += __shfl_xor(s, 8, 16);
    const float inv = 1.0f / s;
    if (ln15 == 0) m_ws[b*NC + c0 + rloc] = mx + smf[SCS_F + rloc];
    #pragma unroll
    for (int n = 0; n < 4; ++n)
      sm[P_OFF + rloc*PITCH + ln15 + 16*n] = f2bf(sv[n] * inv);
  }
  __syncthreads();   // P writes visible before pa loads

  // P fragments (A-operand), loaded once; P region never overwritten below
  bf16x8 pa[2];
  #pragma unroll
  for (int kk = 0; kk < 2; ++kk)
    pa[kk] = *(const bf16x8*)&sm[P_OFF + (w*16 + ln15)*PITCH + kk*32 + g*8];

  // phase-B loader mapping (R2-proven): thread stages q-row lq, 16 d values
  const int lq  = t >> 2;
  const int ld0 = (t & 3) * 16;

  // ---------- Phase B: aq = P @ query (K=64), direct f32 stores to G part 1 ----------
  for (int dc = 0; dc < 8; ++dc) {
    const int d0 = dc * 64;
    __syncthreads();   // prior chunk's qT reads done
    {
      const float* qrow = qry + ((size_t)(b*NQ + lq))*ND + d0 + ld0;
      #pragma unroll
      for (int v = 0; v < 4; ++v) {
        const float4 qv = *(const float4*)(qrow + v*4);
        const int dd = ld0 + v*4;
        sm[CM_OFF + (dd+0)*PITCH + (lq ^ qswz(dd+0))] = f2bf(qv.x);
        sm[CM_OFF + (dd+1)*PITCH + (lq ^ qswz(dd+1))] = f2bf(qv.y);
        sm[CM_OFF + (dd+2)*PITCH + (lq ^ qswz(dd+2))] = f2bf(qv.z);
        sm[CM_OFF + (dd+3)*PITCH + (lq ^ qswz(dd+3))] = f2bf(qv.w);
      }
    }
    __syncthreads();
    f32x4 acc2[4] = {};
    #pragma unroll
    for (int kk = 0; kk < 2; ++kk)
      #pragma unroll
      for (int n = 0; n < 4; ++n) {
        const int dd = n*16 + ln15;
        const bf16x8 bq = *(const bf16x8*)&sm[CM_OFF + dd*PITCH + ((kk*32 + g*8) ^ qswz(dd))];
        acc2[n] = __builtin_amdgcn_mfma_f32_16x16x32_bf16(pa[kk], bq, acc2[n], 0, 0, 0);
      }
    // direct stores: lane (g,ln15) writes aq[w*16+g*4+reg][d0+n*16+ln15]
    #pragma unroll
    for (int reg = 0; reg < 4; ++reg) {
      float* grow = G + ((size_t)(b*NC + c0 + w*16 + g*4 + reg))*2048 + 512 + d0;
      #pragma unroll
      for (int n = 0; n < 4; ++n)
        grow[n*16 + ln15] = acc2[n][reg];
    }
  }
}

// ============ k2: b = softmax_c(m); attended_context (verbatim R2, proven) ============
__global__ __launch_bounds__(256) void k2_partial(
    const float* __restrict__ ctx, const float* __restrict__ m_ws, float* __restrict__ pc)
{
  const int t  = threadIdx.x;
  const int b  = blockIdx.x >> 4;
  const int ch = blockIdx.x & 15;
  __shared__ float r8[8];
  __shared__ float wts[32];

  const float v0 = m_ws[b*NC + t];
  const float v1 = m_ws[b*NC + 256 + t];
  float mx = fmaxf(v0, v1);
  #pragma unroll
  for (int o = 32; o; o >>= 1) mx = fmaxf(mx, __shfl_xor(mx, o, 64));
  if ((t & 63) == 0) r8[t >> 6] = mx;
  __syncthreads();
  mx = fmaxf(fmaxf(r8[0], r8[1]), fmaxf(r8[2], r8[3]));
  float e = __expf(v0 - mx) + __expf(v1 - mx);
  #pragma unroll
  for (int o = 32; o; o >>= 1) e += __shfl_xor(e, o, 64);
  if ((t & 63) == 0) r8[4 + (t >> 6)] = e;
  __syncthreads();
  const float denom = r8[4] + r8[5] + r8[6] + r8[7];
  if (t < 32) wts[t] = __expf(m_ws[b*NC + ch*32 + t] - mx) / denom;
  __syncthreads();

  float s0 = 0.f, s1 = 0.f;
  const float* base = ctx + ((size_t)(b*NC + ch*32))*ND;
  for (int c = 0; c < 32; ++c) {
    const float w = wts[c];
    s0 += w * base[(size_t)c*ND + t];
    s1 += w * base[(size_t)c*ND + t + 256];
  }
  pc[((size_t)(b*16 + ch))*ND + t]       = s0;
  pc[((size_t)(b*16 + ch))*ND + t + 256] = s1;
}

__global__ __launch_bounds__(512) void k2_reduce(
    const float* __restrict__ pc, float* __restrict__ ac)
{
  const int b = blockIdx.x;
  const int d = threadIdx.x;
  float s = 0.f;
  #pragma unroll
  for (int ch = 0; ch < 16; ++ch) s += pc[((size_t)(b*16 + ch))*ND + d];
  ac[b*ND + d] = s;
}

// ============ kFinal: barrier-free streamer for G parts 0, 2, 3 ============
// Reads ctx (L3-hot) + part 1 (aq, written by kA) + ac; writes 96 MB.
__global__ __launch_bounds__(256) void kFinal(
    const float* __restrict__ ctx, const float* __restrict__ ac, float* __restrict__ G)
{
  const size_t e = ((size_t)blockIdx.x*256 + threadIdx.x) * 8;
  const int b = (int)(e >> 18);          // / (512*512)
  const int r = (int)(e & 262143);
  const int c = r >> 9;
  const int d = r & 511;
  float* gp = G + ((size_t)(b*NC + c))*2048 + d;
  const float4 x0 = *(const float4*)(ctx + e);
  const float4 x1 = *(const float4*)(ctx + e + 4);
  const float4 q0 = *(const float4*)(gp + 512);       // aq (part 1)
  const float4 q1 = *(const float4*)(gp + 512 + 4);
  const float4 a0 = *(const float4*)(ac + b*ND + d);
  const float4 a1 = *(const float4*)(ac + b*ND + d + 4);
  *(float4*)(gp)            = x0;                                                      // part 0
  *(float4*)(gp + 4)        = x1;
  *(float4*)(gp + 1024)     = make_float4(x0.x*q0.x, x0.y*q0.y, x0.z*q0.z, x0.w*q0.w); // part 2
  *(float4*)(gp + 1024 + 4) = make_float4(x1.x*q1.x, x1.y*q1.y, x1.z*q1.z, x1.w*q1.w);
  *(float4*)(gp + 1536)     = make_float4(x0.x*a0.x, x0.y*a0.y, x0.z*a0.z, x0.w*a0.w); // part 3
  *(float4*)(gp + 1536 + 4) = make_float4(x1.x*a1.x, x1.y*a1.y, x1.z*a1.z, x1.w*a1.w);
}

extern "C" void kernel_launch(void* const* d_in, const int* in_sizes, int n_in,
                              void* d_out, int out_size, void* d_ws, size_t ws_size,
                              hipStream_t stream)
{
  const float* ctx = (const float*)d_in[0];
  const float* qry = (const float*)d_in[1];
  const float* W   = (const float*)d_in[2];
  float* G = (float*)d_out;

  float* m_ws = (float*)d_ws;            // [32][512]
  float* pc   = m_ws + NB*NC;            // [32][16][512]
  float* ac   = pc + (size_t)NB*16*ND;   // [32][512]

  kA        <<<dim3(NB*8),  dim3(256), 0, stream>>>(ctx, qry, W, G, m_ws);
  k2_partial<<<dim3(NB*16), dim3(256), 0, stream>>>(ctx, m_ws, pc);
  k2_reduce <<<dim3(NB),    dim3(512), 0, stream>>>(pc, ac);
  kFinal    <<<dim3((NB*NC*ND)/(256*8)), dim3(256), 0, stream>>>(ctx, ac, G);
}

// Round 6
// 77.019 us; speedup vs baseline: 1.0313x; 1.0313x over previous
//
#include <hip/hip_runtime.h>
#include <cstdint>

#define NB 32
#define NC 512
#define NQ 64
#define ND 512

typedef __attribute__((ext_vector_type(8))) short bf16x8;   // 8 bf16 (4 VGPRs)
typedef __attribute__((ext_vector_type(4))) float f32x4;

__device__ __forceinline__ short f2bf(float f) {   // RNE f32 -> bf16
  union { float f; unsigned u; } v; v.f = f;
  v.u += 0x7fffu + ((v.u >> 16) & 1u);
  return (short)(v.u >> 16);
}

// ============ kPrep: q_bf16 [b][q][d], qT_bf16 [b][d][q], s_q[b][q] ============
__global__ __launch_bounds__(512) void kPrep(
    const float* __restrict__ qry, const float* __restrict__ W,
    short* __restrict__ qbf, short* __restrict__ qTbf, float* __restrict__ s_q)
{
  __shared__ short lq[NQ*ND];
  const int b = blockIdx.x;
  const int t = threadIdx.x;
  const int r = t >> 3;            // q row, 8 threads/row
  const int cb = (t & 7) * 64;     // 64-d slice
  const float* qrow = qry + ((size_t)(b*NQ + r))*ND + cb;
  float sq = 0.f;
  #pragma unroll
  for (int i = 0; i < 16; ++i) {
    const float4 qv = *(const float4*)(qrow + i*4);
    const float4 wv = *(const float4*)(W + ND + cb + i*4);
    sq += qv.x*wv.x + qv.y*wv.y + qv.z*wv.z + qv.w*wv.w;
    short4 s; s.x=f2bf(qv.x); s.y=f2bf(qv.y); s.z=f2bf(qv.z); s.w=f2bf(qv.w);
    *(short4*)&qbf[((size_t)(b*NQ + r))*ND + cb + i*4] = s;
    *(short4*)&lq[r*ND + cb + i*4] = s;
  }
  sq += __shfl_xor(sq, 1, 8); sq += __shfl_xor(sq, 2, 8); sq += __shfl_xor(sq, 4, 8);
  if ((t & 7) == 0) s_q[b*NQ + r] = sq;
  __syncthreads();
  // transpose: thread t = d, write qT row [d][0..63]
  const int d = t;
  short* qTrow = qTbf + ((size_t)(b*ND + d))*NQ;
  #pragma unroll
  for (int j = 0; j < 16; ++j) {
    short4 h;
    h.x = lq[(j*4+0)*ND + d];
    h.y = lq[(j*4+1)*ND + d];
    h.z = lq[(j*4+2)*ND + d];
    h.w = lq[(j*4+3)*ND + d];
    *(short4*)&qTrow[j*4] = h;
  }
}

// ============ kS: GEMM1(+s_c) + softmax + GEMM2 + stream G parts 0,1,2 ============
// One independent wave per block, 16 c-rows. All LDS wave-private.
__global__ __launch_bounds__(64) void kS(
    const float* __restrict__ ctx, const float* __restrict__ W,
    const short* __restrict__ qbf, const short* __restrict__ qTbf,
    const float* __restrict__ s_q, float* __restrict__ G, float* __restrict__ m_ws)
{
  __shared__ __align__(16) short P[16*72];    // probs bf16, pitch 72
  __shared__ __align__(16) float aqf[16*68];  // aq f32 transpose buffer
  __shared__ float scf[16];                   // s_c

  const int t    = threadIdx.x;
  const int ln15 = t & 15;
  const int g    = t >> 4;
  const int bid  = (int)blockIdx.x;
  const int swz  = (bid & 7) * 128 + (bid >> 3);   // XCD-contiguous (1024 % 8 == 0)
  const int b    = swz >> 5;
  const int c0   = (swz & 31) * 16;

  const float* crow = ctx + ((size_t)(b*NC + c0 + ln15))*ND;

  f32x4 acc[4] = {};
  float scp = 0.f;

  // ---- GEMM1: S = (ctx*w_m) @ q^T; A-frags built in registers, B-frags from global bf16 ----
  #pragma unroll 2
  for (int kc = 0; kc < 8; ++kc) {
    #pragma unroll
    for (int kk = 0; kk < 2; ++kk) {
      const int dd = kc*64 + kk*32 + g*8;
      const float4 c0v = *(const float4*)(crow + dd);
      const float4 c1v = *(const float4*)(crow + dd + 4);
      const float4 wc0 = *(const float4*)(W + dd);
      const float4 wc1 = *(const float4*)(W + dd + 4);
      const float4 wm0 = *(const float4*)(W + 2*ND + dd);
      const float4 wm1 = *(const float4*)(W + 2*ND + dd + 4);
      scp += c0v.x*wc0.x + c0v.y*wc0.y + c0v.z*wc0.z + c0v.w*wc0.w
           + c1v.x*wc1.x + c1v.y*wc1.y + c1v.z*wc1.z + c1v.w*wc1.w;
      bf16x8 a;
      a[0]=f2bf(c0v.x*wm0.x); a[1]=f2bf(c0v.y*wm0.y); a[2]=f2bf(c0v.z*wm0.z); a[3]=f2bf(c0v.w*wm0.w);
      a[4]=f2bf(c1v.x*wm1.x); a[5]=f2bf(c1v.y*wm1.y); a[6]=f2bf(c1v.z*wm1.z); a[7]=f2bf(c1v.w*wm1.w);
      #pragma unroll
      for (int n = 0; n < 4; ++n) {
        const bf16x8 bq = *(const bf16x8*)&qbf[((size_t)(b*NQ + n*16 + ln15))*ND + dd];
        acc[n] = __builtin_amdgcn_mfma_f32_16x16x32_bf16(a, bq, acc[n], 0, 0, 0);
      }
    }
  }

  // s_c for row ln15: reduce over the 4 g-lanes
  scp += __shfl_xor(scp, 16, 64);
  scp += __shfl_xor(scp, 32, 64);
  if (g == 0) scf[ln15] = scp;
  __syncthreads();

  float sqv[4];
  #pragma unroll
  for (int n = 0; n < 4; ++n) sqv[n] = s_q[b*NQ + n*16 + ln15];

  // ---- softmax over q (s_c cancels; added only to stored rowmax) ----
  #pragma unroll
  for (int reg = 0; reg < 4; ++reg) {
    const int rloc = g*4 + reg;          // C/D row mapping
    float sv[4];
    #pragma unroll
    for (int n = 0; n < 4; ++n) sv[n] = acc[n][reg] + sqv[n];
    float mx = fmaxf(fmaxf(sv[0], sv[1]), fmaxf(sv[2], sv[3]));
    mx = fmaxf(mx, __shfl_xor(mx, 1, 16));
    mx = fmaxf(mx, __shfl_xor(mx, 2, 16));
    mx = fmaxf(mx, __shfl_xor(mx, 4, 16));
    mx = fmaxf(mx, __shfl_xor(mx, 8, 16));
    float s = 0.f;
    #pragma unroll
    for (int n = 0; n < 4; ++n) { sv[n] = __expf(sv[n] - mx); s += sv[n]; }
    s += __shfl_xor(s, 1, 16); s += __shfl_xor(s, 2, 16);
    s += __shfl_xor(s, 4, 16); s += __shfl_xor(s, 8, 16);
    const float inv = 1.0f / s;
    if (ln15 == 0) m_ws[b*NC + c0 + rloc] = mx + scf[rloc];
    #pragma unroll
    for (int n = 0; n < 4; ++n)
      P[rloc*72 + ln15 + 16*n] = f2bf(sv[n] * inv);
  }
  __syncthreads();   // P visible before fragment loads (R4's missing barrier)

  bf16x8 pa[2];
  pa[0] = *(const bf16x8*)&P[ln15*72 + g*8];
  pa[1] = *(const bf16x8*)&P[ln15*72 + 32 + g*8];

  // ---- GEMM2: aq = P @ query (K=64); B-frags from global qT; fused streaming epilogue ----
  for (int dc = 0; dc < 8; ++dc) {
    const int d0 = dc * 64;
    f32x4 acc2[4] = {};
    #pragma unroll
    for (int kk = 0; kk < 2; ++kk)
      #pragma unroll
      for (int n = 0; n < 4; ++n) {
        const bf16x8 bq = *(const bf16x8*)&qTbf[((size_t)(b*ND + d0 + n*16 + ln15))*NQ + kk*32 + g*8];
        acc2[n] = __builtin_amdgcn_mfma_f32_16x16x32_bf16(pa[kk], bq, acc2[n], 0, 0, 0);
      }
    __syncthreads();   // prior chunk's aqf reads complete
    #pragma unroll
    for (int n = 0; n < 4; ++n)
      #pragma unroll
      for (int reg = 0; reg < 4; ++reg)
        aqf[(g*4 + reg)*68 + n*16 + ln15] = acc2[n][reg];
    __syncthreads();   // aqf visible
    #pragma unroll
    for (int pass = 0; pass < 4; ++pass) {
      const int r = pass*4 + g;
      const float4 aq4 = *(const float4*)&aqf[r*68 + ln15*4];
      const float4 cv  = *(const float4*)(ctx + ((size_t)(b*NC + c0 + r))*ND + d0 + ln15*4);
      float* gp = G + ((size_t)(b*NC + c0 + r))*2048 + d0 + ln15*4;
      *(float4*)(gp)        = cv;                                            // part 0
      *(float4*)(gp + 512)  = aq4;                                           // part 1
      *(float4*)(gp + 1024) = make_float4(cv.x*aq4.x, cv.y*aq4.y,
                                          cv.z*aq4.z, cv.w*aq4.w);           // part 2
    }
  }
}

// ============ k2: b = softmax_c(m); attended_context (proven) ============
__global__ __launch_bounds__(256) void k2_partial(
    const float* __restrict__ ctx, const float* __restrict__ m_ws, float* __restrict__ pc)
{
  const int t  = threadIdx.x;
  const int b  = blockIdx.x >> 4;
  const int ch = blockIdx.x & 15;
  __shared__ float r8[8];
  __shared__ float wts[32];

  const float v0 = m_ws[b*NC + t];
  const float v1 = m_ws[b*NC + 256 + t];
  float mx = fmaxf(v0, v1);
  #pragma unroll
  for (int o = 32; o; o >>= 1) mx = fmaxf(mx, __shfl_xor(mx, o, 64));
  if ((t & 63) == 0) r8[t >> 6] = mx;
  __syncthreads();
  mx = fmaxf(fmaxf(r8[0], r8[1]), fmaxf(r8[2], r8[3]));
  float e = __expf(v0 - mx) + __expf(v1 - mx);
  #pragma unroll
  for (int o = 32; o; o >>= 1) e += __shfl_xor(e, o, 64);
  if ((t & 63) == 0) r8[4 + (t >> 6)] = e;
  __syncthreads();
  const float denom = r8[4] + r8[5] + r8[6] + r8[7];
  if (t < 32) wts[t] = __expf(m_ws[b*NC + ch*32 + t] - mx) / denom;
  __syncthreads();

  float s0 = 0.f, s1 = 0.f;
  const float* base = ctx + ((size_t)(b*NC + ch*32))*ND;
  for (int c = 0; c < 32; ++c) {
    const float w = wts[c];
    s0 += w * base[(size_t)c*ND + t];
    s1 += w * base[(size_t)c*ND + t + 256];
  }
  pc[((size_t)(b*16 + ch))*ND + t]       = s0;
  pc[((size_t)(b*16 + ch))*ND + t + 256] = s1;
}

__global__ __launch_bounds__(512) void k2_reduce(
    const float* __restrict__ pc, float* __restrict__ ac)
{
  const int b = blockIdx.x;
  const int d = threadIdx.x;
  float s = 0.f;
  #pragma unroll
  for (int ch = 0; ch < 16; ++ch) s += pc[((size_t)(b*16 + ch))*ND + d];
  ac[b*ND + d] = s;
}

// ============ kFinal: G part 3 = ctx * attended_context (proven) ============
__global__ __launch_bounds__(256) void kFinal(
    const float* __restrict__ ctx, const float* __restrict__ ac, float* __restrict__ G)
{
  const size_t e = ((size_t)blockIdx.x*256 + threadIdx.x) * 8;
  const int b = (int)(e >> 18);
  const int r = (int)(e & 262143);
  const int c = r >> 9;
  const int d = r & 511;
  const float4 x0 = *(const float4*)(ctx + e);
  const float4 x1 = *(const float4*)(ctx + e + 4);
  const float4 a0 = *(const float4*)(ac + b*ND + d);
  const float4 a1 = *(const float4*)(ac + b*ND + d + 4);
  float* gp = G + ((size_t)(b*NC + c))*2048 + 1536 + d;
  *(float4*)(gp)     = make_float4(x0.x*a0.x, x0.y*a0.y, x0.z*a0.z, x0.w*a0.w);
  *(float4*)(gp + 4) = make_float4(x1.x*a1.x, x1.y*a1.y, x1.z*a1.z, x1.w*a1.w);
}

extern "C" void kernel_launch(void* const* d_in, const int* in_sizes, int n_in,
                              void* d_out, int out_size, void* d_ws, size_t ws_size,
                              hipStream_t stream)
{
  const float* ctx = (const float*)d_in[0];
  const float* qry = (const float*)d_in[1];
  const float* W   = (const float*)d_in[2];
  float* G = (float*)d_out;

  float* ws   = (float*)d_ws;
  float* m_ws = ws;                        // [32][512]
  float* pc   = ws + 16384;                // [32][16][512]
  float* ac   = ws + 278528;               // [32][512]
  float* s_q  = ws + 294912;               // [32][64]
  short* qbf  = (short*)(ws + 296960);     // [32][64][512] bf16
  short* qTbf = qbf + (size_t)NB*NQ*ND;    // [32][512][64] bf16

  kPrep     <<<dim3(NB),    dim3(512), 0, stream>>>(qry, W, qbf, qTbf, s_q);
  kS        <<<dim3(NB*32), dim3(64),  0, stream>>>(ctx, W, qbf, qTbf, s_q, G, m_ws);
  k2_partial<<<dim3(NB*16), dim3(256), 0, stream>>>(ctx, m_ws, pc);
  k2_reduce <<<dim3(NB),    dim3(512), 0, stream>>>(pc, ac);
  kFinal    <<<dim3((NB*NC*ND)/(256*8)), dim3(256), 0, stream>>>(ctx, ac, G);
}